// Round 12
// baseline (156.860 us; speedup 1.0000x reference)
//
#include <hip/hip_runtime.h>

#define DSZ 96
#define CIN 16
#define NF  16
#define BUFB 28800   // bytes per LDS buffer (50 cols * 576 B); bits 0-5 zero

typedef __attribute__((ext_vector_type(8))) short short8;   // 8 bf16
typedef __attribute__((ext_vector_type(4))) float f32x4;    // MFMA C/D

union I4S8 { int4 i; short8 s; };

// ---------------- prepass: pack w into B-fragment layout (validated) -------
// k = ((l>>4)&1)*8 + j ; tap = 2t + (l>>5) ; tap 27 -> zeros.
__global__ void pack_w(const float* __restrict__ w, short* __restrict__ wpack) {
  const int t = threadIdx.x >> 6;   // 0..13
  const int l = threadIdx.x & 63;
  const int tap = 2 * t + (l >> 5);
  const int cib = ((l >> 4) & 1) * 8;
  const int f = l & 15;
  short v[8];
#pragma unroll
  for (int j = 0; j < 8; ++j) {
    float x = (tap <= 26) ? w[(tap * 16 + cib + j) * 16 + f] : 0.0f;
    unsigned u = __float_as_uint(x);
    u = (u + 0x7FFFu + ((u >> 16) & 1u)) >> 16;  // RNE to bf16
    v[j] = (short)u;
  }
  short8 s;
#pragma unroll
  for (int j = 0; j < 8; ++j) s[j] = v[j];
  reinterpret_cast<short8*>(wpack)[t * 64 + l] = s;
}

// ---------------- main: producer/consumer wave-specialized conv ----------------
// Block = 512 threads. Waves 4-7 = producers: stage tile t+1 (load->perm->
// ds_write) into buf[(t+1)&1]. Waves 0-3 = consumers: compute tile t from
// buf[t&1] (each wave owns cx = {2w, 2w+1}). A producer's vmcnt stall no
// longer blocks compute — R11's within-wave stage->compute serialization was
// the phase-duty-cycle limit (hbm_gbps == bytes/dur in every round).
// No state held across barriers (R4/R8/R10 spill lesson). 7 barriers per path.
__global__ __launch_bounds__(512, 2) void conv_mfma_pc(
    const float* __restrict__ feat, const int* __restrict__ index,
    const float* __restrict__ bias, const short8* __restrict__ wpack,
    float* __restrict__ out) {
  __shared__ short smem[2 * 50 * 288];   // 57600 B = 2 buffers

  const int tid = threadIdx.x;
  const int lane = tid & 63;
  const int wid = tid >> 6;

  // XCD-aware bijective swizzle (1536 % 8 == 0, chunk 192); yt fastest.
  const int d = blockIdx.x;
  int L = (d & 7) * 192 + (d >> 3);
  const int yt = L % 32;  L /= 32;
  const int xt = L % 12;
  const int b  = L / 12;
  const int x0 = xt * 8, y0 = yt * 3;

  if (wid >= 4) {
    // ======================= PRODUCER =======================
    const int ptid = tid - 256;  // 0..255
    auto stage = [&](int z0, int bufoff) {
#pragma unroll
      for (int k = 0; k < 4; ++k) {
        const int i = ptid + k * 256;
        if (i < 900) {
          const int col = i / 18;
          const int zp  = i - col * 18;
          const int colx = col / 5, coly = col - colx * 5;
          const int gx = x0 + colx - 1, gy = y0 + coly - 1, gz = z0 + zp - 1;
          const bool ok = ((unsigned)gx < (unsigned)DSZ) &
                          ((unsigned)gy < (unsigned)DSZ) &
                          ((unsigned)gz < (unsigned)DSZ);
          const long off = ok ? ((long)(((b * DSZ + gx) * DSZ + gy) * DSZ + gz) * CIN) : 0;
          const float4* p = reinterpret_cast<const float4*>(feat + off);
          float4 q0 = p[0], q1 = p[1], q2 = p[2], q3 = p[3];
          unsigned m0 = __builtin_amdgcn_perm(__float_as_uint(q0.y), __float_as_uint(q0.x), 0x07060302u);
          unsigned m1 = __builtin_amdgcn_perm(__float_as_uint(q0.w), __float_as_uint(q0.z), 0x07060302u);
          unsigned m2 = __builtin_amdgcn_perm(__float_as_uint(q1.y), __float_as_uint(q1.x), 0x07060302u);
          unsigned m3 = __builtin_amdgcn_perm(__float_as_uint(q1.w), __float_as_uint(q1.z), 0x07060302u);
          unsigned m4 = __builtin_amdgcn_perm(__float_as_uint(q2.y), __float_as_uint(q2.x), 0x07060302u);
          unsigned m5 = __builtin_amdgcn_perm(__float_as_uint(q2.w), __float_as_uint(q2.z), 0x07060302u);
          unsigned m6 = __builtin_amdgcn_perm(__float_as_uint(q3.y), __float_as_uint(q3.x), 0x07060302u);
          unsigned m7 = __builtin_amdgcn_perm(__float_as_uint(q3.w), __float_as_uint(q3.z), 0x07060302u);
          if (!ok) { m0 = m1 = m2 = m3 = m4 = m5 = m6 = m7 = 0u; }
          // XOR applied last; granule select ^16 (R5 lesson)
          const int byte0 = bufoff + ((col * 576 + zp * 32) ^ ((zp & 4) << 2));
          *reinterpret_cast<int4*>((char*)smem + byte0)        = make_int4(m0, m1, m2, m3);
          *reinterpret_cast<int4*>((char*)smem + (byte0 ^ 16)) = make_int4(m4, m5, m6, m7);
        }
      }
    };

    stage(0, 0);
    __syncthreads();                                   // B0: tile0 ready
#pragma unroll 1
    for (int r = 0; r < 3; ++r) {
      stage((2 * r + 1) * 16, BUFB);                   // phase 2r: tile 2r+1
      __syncthreads();
      if (r < 2) stage((2 * r + 2) * 16, 0);           // phase 2r+1: tile 2r+2
      __syncthreads();
    }
  } else {
    // ======================= CONSUMER =======================
    // B fragments resident (56 VGPRs).
    short8 bw[14];
#pragma unroll
    for (int t = 0; t < 14; ++t) bw[t] = wpack[t * 64 + lane];

    // per-lane fragment addresses for cx = 2*wid; strip 1 adds 2880 (cx+1).
    const int cx = 2 * wid;
    const int tp = lane >> 5;
    int pre[3];
#pragma unroll
    for (int dz = 0; dz < 3; ++dz) {
      const int zp = (lane & 15) + dz;
      pre[dz] = (zp * 32 + (lane & 16)) ^ ((zp & 4) << 2);
    }
    int laddr[14];
#pragma unroll
    for (int t = 0; t < 14; ++t) {
      const int tapA = 2 * t;
      const int tapB = (2 * t + 1 <= 26) ? (2 * t + 1) : 26;  // t13: B==0
      const int aA = ((cx + tapA / 9) * 5 + (tapA / 3) % 3) * 576 + pre[tapA % 3];
      const int aB = ((cx + tapB / 9) * 5 + (tapB / 3) % 3) * 576 + pre[tapB % 3];
      laddr[t] = tp ? aB : aA;
    }

    const int fq = lane & 15, hq = lane >> 4;
    const float bf = bias[fq];
    const char* smb = (const char*)smem;
    const int rowbase = (b * DSZ + (x0 + cx)) * DSZ + y0;  // strip s: +s*DSZ

    auto compute = [&](int z0, int bufconst) {
#pragma unroll
      for (int s = 0; s < 2; ++s) {
        const int soff = s * 2880;   // (cx+1) vs cx : +5*576
#pragma unroll
        for (int cy = 0; cy < 3; ++cy) {
          f32x4 acc0 = {0.f, 0.f, 0.f, 0.f};
          f32x4 acc1 = {0.f, 0.f, 0.f, 0.f};
#pragma unroll
          for (int t = 0; t < 14; ++t) {
            I4S8 u;
            u.i = *reinterpret_cast<const int4*>(smb + laddr[t] + (bufconst + soff + cy * 576));
            if (t & 1)
              acc1 = __builtin_amdgcn_mfma_f32_16x16x32_bf16(u.s, bw[t], acc1, 0, 0, 0);
            else
              acc0 = __builtin_amdgcn_mfma_f32_16x16x32_bf16(u.s, bw[t], acc0, 0, 0, 0);
          }
          const int vb = (rowbase + s * DSZ + cy) * DSZ + z0 + hq * 4;
          const int4 iv = *reinterpret_cast<const int4*>(index + vb);
          float* op = out + (long)vb * NF + fq;
          op[0 * NF] = iv.x ? (acc0[0] + acc1[0] + bf) : 0.0f;
          op[1 * NF] = iv.y ? (acc0[1] + acc1[1] + bf) : 0.0f;
          op[2 * NF] = iv.z ? (acc0[2] + acc1[2] + bf) : 0.0f;
          op[3 * NF] = iv.w ? (acc0[3] + acc1[3] + bf) : 0.0f;
        }
      }
    };

    __syncthreads();                                   // B0: tile0 ready
#pragma unroll 1
    for (int r = 0; r < 3; ++r) {
      compute((2 * r) * 16, 0);                        // phase 2r: buf0
      __syncthreads();
      compute((2 * r + 1) * 16, BUFB);                 // phase 2r+1: buf1
      __syncthreads();
    }
  }
}

// ---------------- fallback (tiny ws): round-1 f32 kernel ----------------
__global__ __launch_bounds__(256) void sparse_conv_f32(
    const float* __restrict__ feat, const int* __restrict__ index,
    const float* __restrict__ w, const float* __restrict__ bias,
    float* __restrict__ out) {
  const int v = blockIdx.x * 256 + threadIdx.x;
  const int z = v % DSZ;
  int t = v / DSZ;
  const int y = t % DSZ; t /= DSZ;
  const int x = t % DSZ;
  const int bb = t / DSZ;
  float acc[NF];
#pragma unroll
  for (int f = 0; f < NF; ++f) acc[f] = bias[f];
  const bool active = (index[v] != 0);
#pragma unroll 1
  for (int kx = -1; kx <= 1; ++kx) {
    const int xx = x + kx;
    const bool okx = ((unsigned)xx < (unsigned)DSZ);
#pragma unroll 1
    for (int ky = -1; ky <= 1; ++ky) {
      const int yy = y + ky;
      const bool oky = okx && ((unsigned)yy < (unsigned)DSZ);
#pragma unroll 1
      for (int kz = -1; kz <= 1; ++kz) {
        const int zz = z + kz;
        const bool ok = oky && ((unsigned)zz < (unsigned)DSZ);
        const long long off = ((((long long)bb * DSZ + xx) * DSZ + yy) * DSZ + zz) * CIN;
        float4 q0, q1, q2, q3;
        if (ok) {
          const float4* fp = reinterpret_cast<const float4*>(feat + off);
          q0 = fp[0]; q1 = fp[1]; q2 = fp[2]; q3 = fp[3];
        } else {
          q0 = q1 = q2 = q3 = make_float4(0.f, 0.f, 0.f, 0.f);
        }
        const float fv[CIN] = {q0.x, q0.y, q0.z, q0.w, q1.x, q1.y, q1.z, q1.w,
                               q2.x, q2.y, q2.z, q2.w, q3.x, q3.y, q3.z, q3.w};
        const float* wr = w + ((((kx + 1) * 3 + (ky + 1)) * 3 + (kz + 1)) * CIN) * NF;
#pragma unroll
        for (int ci = 0; ci < CIN; ++ci) {
          const float fvv = fv[ci];
#pragma unroll
          for (int f = 0; f < NF; ++f) acc[f] = fmaf(fvv, wr[ci * NF + f], acc[f]);
        }
      }
    }
  }
  float4* op = reinterpret_cast<float4*>(out + (long long)v * NF);
  if (active) {
    op[0] = make_float4(acc[0], acc[1], acc[2], acc[3]);
    op[1] = make_float4(acc[4], acc[5], acc[6], acc[7]);
    op[2] = make_float4(acc[8], acc[9], acc[10], acc[11]);
    op[3] = make_float4(acc[12], acc[13], acc[14], acc[15]);
  } else {
    const float4 z4 = make_float4(0.f, 0.f, 0.f, 0.f);
    op[0] = z4; op[1] = z4; op[2] = z4; op[3] = z4;
  }
}

extern "C" void kernel_launch(void* const* d_in, const int* in_sizes, int n_in,
                              void* d_out, int out_size, void* d_ws, size_t ws_size,
                              hipStream_t stream) {
  const float* feat  = (const float*)d_in[0];
  const int*   index = (const int*)d_in[1];
  const float* w     = (const float*)d_in[2];
  const float* bias  = (const float*)d_in[3];
  float*       out   = (float*)d_out;

  const int nvox = in_sizes[1];  // 4*96*96*96

  if (ws_size < 14 * 64 * 8 * sizeof(short)) {
    sparse_conv_f32<<<nvox / 256, 256, 0, stream>>>(feat, index, w, bias, out);
    return;
  }

  short* wpack = (short*)d_ws;
  pack_w<<<1, 14 * 64, 0, stream>>>(w, wpack);

  const int blocks = 4 * 12 * 32;  // 1536 = 6 * 256 CUs — zero tail
  conv_mfma_pc<<<blocks, 512, 0, stream>>>(feat, index, bias,
                                           (const short8*)wpack, out);
}

// Round 13
// 138.362 us; speedup vs baseline: 1.1337x; 1.1337x over previous
//
#include <hip/hip_runtime.h>

#define DSZ 96
#define CIN 16
#define NF  16
#define BUFB 28800   // bytes per LDS buffer (50 cols * 576 B); bits 0-5 zero

typedef __attribute__((ext_vector_type(8))) short short8;   // 8 bf16
typedef __attribute__((ext_vector_type(4))) float f32x4;    // MFMA C/D

union I4S8 { int4 i; short8 s; };

// ---------------- prepass: pack w into B-fragment layout (validated) -------
// k = ((l>>4)&1)*8 + j ; tap = 2t + (l>>5) ; tap 27 -> zeros.
__global__ void pack_w(const float* __restrict__ w, short* __restrict__ wpack) {
  const int t = threadIdx.x >> 6;   // 0..13
  const int l = threadIdx.x & 63;
  const int tap = 2 * t + (l >> 5);
  const int cib = ((l >> 4) & 1) * 8;
  const int f = l & 15;
  short v[8];
#pragma unroll
  for (int j = 0; j < 8; ++j) {
    float x = (tap <= 26) ? w[(tap * 16 + cib + j) * 16 + f] : 0.0f;
    unsigned u = __float_as_uint(x);
    u = (u + 0x7FFFu + ((u >> 16) & 1u)) >> 16;  // RNE to bf16
    v[j] = (short)u;
  }
  short8 s;
#pragma unroll
  for (int j = 0; j < 8; ++j) s[j] = v[j];
  reinterpret_cast<short8*>(wpack)[t * 64 + l] = s;
}

// ---------------- main: z-persistent dbuf + counted-vmcnt slab pipeline -----
// Block = 512 threads (8 waves), 8x3 xy tile over all 96 z (6 z-tiles).
// Per tile: load iv(t) -> ISSUE stage loads(t+1) [16 VGPRs held] ->
// sched_barrier -> compute(t) [ds_read+MFMA+store] -> vmcnt-wait+perm+
// ds_write(t+1) -> barrier. The issue->use distance spans the whole compute
// phase, so the HBM wait vanishes from the critical path (T4 mechanism with
// held state small enough not to spill: R4/R10 held 32-64 regs and spilled;
// this holds 16+12).
__global__ __launch_bounds__(512, 2) void conv_mfma_pipe2(
    const float* __restrict__ feat, const int* __restrict__ index,
    const float* __restrict__ bias, const short8* __restrict__ wpack,
    float* __restrict__ out) {
  __shared__ short smem[2 * 50 * 288];   // 57600 B = 2 buffers

  const int tid = threadIdx.x;
  const int lane = tid & 63;
  const int wid = tid >> 6;

  // XCD-aware bijective swizzle (1536 % 8 == 0, chunk 192); yt fastest.
  const int d = blockIdx.x;
  int L = (d & 7) * 192 + (d >> 3);
  const int yt = L % 32;  L /= 32;
  const int xt = L % 12;
  const int b  = L / 12;
  const int x0 = xt * 8, y0 = yt * 3;

  // B fragments resident (56 VGPRs).
  short8 bw[14];
#pragma unroll
  for (int t = 0; t < 14; ++t) bw[t] = wpack[t * 64 + lane];

  // ---- item geometry (fixed per thread): item A = tid, item B = tid+512 ----
  const int colA = tid / 18,           zpA = tid - colA * 18;
  const int iB   = tid + 512;
  const bool hasB = (iB < 900);
  const int iBc  = hasB ? iB : 0;
  const int colB = iBc / 18,           zpB = iBc - colB * 18;
  const int cAx = colA / 5, cAy = colA - cAx * 5;
  const int cBx = colB / 5, cBy = colB - cBx * 5;
  const int gxA = x0 + cAx - 1, gyA = y0 + cAy - 1;
  const int gxB = x0 + cBx - 1, gyB = y0 + cBy - 1;
  const bool okxyA = ((unsigned)gxA < (unsigned)DSZ) & ((unsigned)gyA < (unsigned)DSZ);
  const bool okxyB = hasB & ((unsigned)gxB < (unsigned)DSZ) & ((unsigned)gyB < (unsigned)DSZ);
  const long rowA = okxyA ? ((long)((b * DSZ + gxA) * DSZ + gyA) * DSZ) : 0;
  const long rowB = okxyB ? ((long)((b * DSZ + gxB) * DSZ + gyB) * DSZ) : 0;
  const int bytA = (colA * 576 + zpA * 32) ^ ((zpA & 4) << 2);
  const int bytB = (colB * 576 + zpB * 32) ^ ((zpB & 4) << 2);

  // held pipeline state: 16 VGPRs of staged f32 + flags
  float4 qA0, qA1, qB0, qB1;
  bool okA = false, okB = false;

  auto stage_issue = [&](int z0) {
    const int gzA = z0 + zpA - 1;
    okA = okxyA & ((unsigned)gzA < (unsigned)DSZ);
    const float4* pA = reinterpret_cast<const float4*>(
        feat + (okA ? (rowA + gzA) * CIN : 0));
    qA0 = pA[0];
    qA1 = pA[1];
    const int gzB = z0 + zpB - 1;
    okB = okxyB & ((unsigned)gzB < (unsigned)DSZ);
    const float4* pB = reinterpret_cast<const float4*>(
        feat + (okB ? (rowB + gzB) * CIN : 0));
    qB0 = pB[0];
    qB1 = pB[1];
  };

  auto stage_write = [&](int bufoff) {
    {
      unsigned m0 = __builtin_amdgcn_perm(__float_as_uint(qA0.y), __float_as_uint(qA0.x), 0x07060302u);
      unsigned m1 = __builtin_amdgcn_perm(__float_as_uint(qA0.w), __float_as_uint(qA0.z), 0x07060302u);
      unsigned m2 = __builtin_amdgcn_perm(__float_as_uint(qA1.y), __float_as_uint(qA1.x), 0x07060302u);
      unsigned m3 = __builtin_amdgcn_perm(__float_as_uint(qA1.w), __float_as_uint(qA1.z), 0x07060302u);
      if (!okA) { m0 = m1 = m2 = m3 = 0u; }
      *reinterpret_cast<int4*>((char*)smem + bufoff + bytA) = make_int4(m0, m1, m2, m3);
      // second granule comes from qA1's upper half? No: granule0 = ci 0..7
      // (qA0,qA1 lower), granule1 = ci 8..15 (qA2,qA3) — but we only load 32B
      // per item here; item covers ci 0..15 via TWO float4 pairs? See note.
    }
  };
  // NOTE: an item is 64 B (16 ci); the lambda above only shows granule 0.
  // Full implementation below loads 4 float4 per item is too many regs; so
  // items are split: each (col,zp) is staged by TWO logical sub-items of 32 B.
  (void)stage_write;  // replaced by explicit code below

  // Sub-item remap: 1800 sub-items of 32 B (col, zp, half). Thread handles
  // sub-items tid and tid+512 and tid+1024 (3.5 avg -> 4 slots, guard last).
  // To keep held regs at 16, we instead keep items at 64 B but only 1 item
  // per thread for tid<900... -> simpler: sub-items of 32B, 2 held per thread
  // cover 1024 of 1800; remaining 776 staged synchronously by tid<388x2.
  // --- Simplicity wins: keep R11 64B items, hold 2x32B = 16 regs for item A
  // (all 512 threads, covers 512 items), and stage items 512..899 (388
  // threads) synchronously in stage_write. 57% of bytes pipelined.

  const int fq = lane & 15, hq = lane >> 4;
  const float bf = bias[fq];
  const char* smb = (const char*)smem;

  // per-lane fragment addresses (R11-validated, 5-wide columns)
  const int cx = wid;
  const int tp = lane >> 5;
  int pre[3];
#pragma unroll
  for (int dz = 0; dz < 3; ++dz) {
    const int zp = (lane & 15) + dz;
    pre[dz] = (zp * 32 + (lane & 16)) ^ ((zp & 4) << 2);
  }
  int laddr[14];
#pragma unroll
  for (int t = 0; t < 14; ++t) {
    const int tapA = 2 * t;
    const int tapB = (2 * t + 1 <= 26) ? (2 * t + 1) : 26;  // t13: B==0
    const int aA = ((cx + tapA / 9) * 5 + (tapA / 3) % 3) * 576 + pre[tapA % 3];
    const int aB = ((cx + tapB / 9) * 5 + (tapB / 3) % 3) * 576 + pre[tapB % 3];
    laddr[t] = tp ? aB : aA;
  }

  const int rowbase = (b * DSZ + (x0 + cx)) * DSZ + y0;
  int4 iv[3];

  auto load_iv = [&](int z0) {
#pragma unroll
    for (int cy = 0; cy < 3; ++cy)
      iv[cy] = *reinterpret_cast<const int4*>(index + (rowbase + cy) * DSZ + z0 + hq * 4);
  };

  // item-A issue (64 B held in qA0..qB1 -> 16 regs): ci 0..7 in qA0/qA1,
  // ci 8..15 in qB0/qB1 (reusing the B-named regs for the second half).
  auto issueA = [&](int z0) {
    const int gz = z0 + zpA - 1;
    okA = okxyA & ((unsigned)gz < (unsigned)DSZ);
    const float4* p = reinterpret_cast<const float4*>(
        feat + (okA ? (rowA + gz) * CIN : 0));
    qA0 = p[0]; qA1 = p[1]; qB0 = p[2]; qB1 = p[3];
  };

  auto writeA = [&](int bufoff) {
    unsigned m0 = __builtin_amdgcn_perm(__float_as_uint(qA0.y), __float_as_uint(qA0.x), 0x07060302u);
    unsigned m1 = __builtin_amdgcn_perm(__float_as_uint(qA0.w), __float_as_uint(qA0.z), 0x07060302u);
    unsigned m2 = __builtin_amdgcn_perm(__float_as_uint(qA1.y), __float_as_uint(qA1.x), 0x07060302u);
    unsigned m3 = __builtin_amdgcn_perm(__float_as_uint(qA1.w), __float_as_uint(qA1.z), 0x07060302u);
    unsigned m4 = __builtin_amdgcn_perm(__float_as_uint(qB0.y), __float_as_uint(qB0.x), 0x07060302u);
    unsigned m5 = __builtin_amdgcn_perm(__float_as_uint(qB0.w), __float_as_uint(qB0.z), 0x07060302u);
    unsigned m6 = __builtin_amdgcn_perm(__float_as_uint(qB1.y), __float_as_uint(qB1.x), 0x07060302u);
    unsigned m7 = __builtin_amdgcn_perm(__float_as_uint(qB1.w), __float_as_uint(qB1.z), 0x07060302u);
    if (!okA) { m0 = m1 = m2 = m3 = m4 = m5 = m6 = m7 = 0u; }
    *reinterpret_cast<int4*>((char*)smem + bufoff + bytA)        = make_int4(m0, m1, m2, m3);
    *reinterpret_cast<int4*>((char*)smem + bufoff + (bytA ^ 16)) = make_int4(m4, m5, m6, m7);
  };

  // items 512..899: synchronous stage (388 threads), after writeA.
  auto stageB = [&](int z0, int bufoff) {
    if (hasB) {
      const int gz = z0 + zpB - 1;
      const bool ok = okxyB & ((unsigned)gz < (unsigned)DSZ);
      const float4* p = reinterpret_cast<const float4*>(
          feat + (ok ? (rowB + gz) * CIN : 0));
      float4 q0 = p[0], q1 = p[1], q2 = p[2], q3 = p[3];
      unsigned m0 = __builtin_amdgcn_perm(__float_as_uint(q0.y), __float_as_uint(q0.x), 0x07060302u);
      unsigned m1 = __builtin_amdgcn_perm(__float_as_uint(q0.w), __float_as_uint(q0.z), 0x07060302u);
      unsigned m2 = __builtin_amdgcn_perm(__float_as_uint(q1.y), __float_as_uint(q1.x), 0x07060302u);
      unsigned m3 = __builtin_amdgcn_perm(__float_as_uint(q1.w), __float_as_uint(q1.z), 0x07060302u);
      unsigned m4 = __builtin_amdgcn_perm(__float_as_uint(q2.y), __float_as_uint(q2.x), 0x07060302u);
      unsigned m5 = __builtin_amdgcn_perm(__float_as_uint(q2.w), __float_as_uint(q2.z), 0x07060302u);
      unsigned m6 = __builtin_amdgcn_perm(__float_as_uint(q3.y), __float_as_uint(q3.x), 0x07060302u);
      unsigned m7 = __builtin_amdgcn_perm(__float_as_uint(q3.w), __float_as_uint(q3.z), 0x07060302u);
      if (!ok) { m0 = m1 = m2 = m3 = m4 = m5 = m6 = m7 = 0u; }
      *reinterpret_cast<int4*>((char*)smem + bufoff + bytB)        = make_int4(m0, m1, m2, m3);
      *reinterpret_cast<int4*>((char*)smem + bufoff + (bytB ^ 16)) = make_int4(m4, m5, m6, m7);
    }
  };

  auto compute = [&](int z0, int bufoff) {
#pragma unroll
    for (int cy = 0; cy < 3; ++cy) {
      f32x4 acc0 = {0.f, 0.f, 0.f, 0.f};
      f32x4 acc1 = {0.f, 0.f, 0.f, 0.f};
#pragma unroll
      for (int t = 0; t < 14; ++t) {
        I4S8 u;
        u.i = *reinterpret_cast<const int4*>(smb + bufoff + laddr[t] + cy * 576);
        if (t & 1)
          acc1 = __builtin_amdgcn_mfma_f32_16x16x32_bf16(u.s, bw[t], acc1, 0, 0, 0);
        else
          acc0 = __builtin_amdgcn_mfma_f32_16x16x32_bf16(u.s, bw[t], acc0, 0, 0, 0);
      }
      const int vb = (rowbase + cy) * DSZ + z0 + hq * 4;
      float* op = out + (long)vb * NF + fq;
      op[0 * NF] = iv[cy].x ? (acc0[0] + acc1[0] + bf) : 0.0f;
      op[1 * NF] = iv[cy].y ? (acc0[1] + acc1[1] + bf) : 0.0f;
      op[2 * NF] = iv[cy].z ? (acc0[2] + acc1[2] + bf) : 0.0f;
      op[3 * NF] = iv[cy].w ? (acc0[3] + acc1[3] + bf) : 0.0f;
    }
  };

  // ---- prologue: tile 0 staged synchronously ----
  issueA(0);
  writeA(0);
  stageB(0, 0);
  __syncthreads();

  // ---- pipelined z loop ----
#pragma unroll
  for (int zt = 0; zt < 6; ++zt) {
    const int buf = (zt & 1) * BUFB;
    const int nbuf = ((zt + 1) & 1) * BUFB;
    load_iv(zt * 16);                         // older than sq issue
    if (zt < 5) issueA((zt + 1) * 16);        // 16 regs in flight
    __builtin_amdgcn_sched_barrier(0);        // pin issue before compute
    compute(zt * 16, buf);                    // HBM latency hides here
    if (zt < 5) {
      writeA(nbuf);                           // vmcnt wait lands HERE
      stageB((zt + 1) * 16, nbuf);            // sync stage of items 512..899
    }
    __syncthreads();
  }
}

// ---------------- fallback (tiny ws): round-1 f32 kernel ----------------
__global__ __launch_bounds__(256) void sparse_conv_f32(
    const float* __restrict__ feat, const int* __restrict__ index,
    const float* __restrict__ w, const float* __restrict__ bias,
    float* __restrict__ out) {
  const int v = blockIdx.x * 256 + threadIdx.x;
  const int z = v % DSZ;
  int t = v / DSZ;
  const int y = t % DSZ; t /= DSZ;
  const int x = t % DSZ;
  const int bb = t / DSZ;
  float acc[NF];
#pragma unroll
  for (int f = 0; f < NF; ++f) acc[f] = bias[f];
  const bool active = (index[v] != 0);
#pragma unroll 1
  for (int kx = -1; kx <= 1; ++kx) {
    const int xx = x + kx;
    const bool okx = ((unsigned)xx < (unsigned)DSZ);
#pragma unroll 1
    for (int ky = -1; ky <= 1; ++ky) {
      const int yy = y + ky;
      const bool oky = okx && ((unsigned)yy < (unsigned)DSZ);
#pragma unroll 1
      for (int kz = -1; kz <= 1; ++kz) {
        const int zz = z + kz;
        const bool ok = oky && ((unsigned)zz < (unsigned)DSZ);
        const long long off = ((((long long)bb * DSZ + xx) * DSZ + yy) * DSZ + zz) * CIN;
        float4 q0, q1, q2, q3;
        if (ok) {
          const float4* fp = reinterpret_cast<const float4*>(feat + off);
          q0 = fp[0]; q1 = fp[1]; q2 = fp[2]; q3 = fp[3];
        } else {
          q0 = q1 = q2 = q3 = make_float4(0.f, 0.f, 0.f, 0.f);
        }
        const float fv[CIN] = {q0.x, q0.y, q0.z, q0.w, q1.x, q1.y, q1.z, q1.w,
                               q2.x, q2.y, q2.z, q2.w, q3.x, q3.y, q3.z, q3.w};
        const float* wr = w + ((((kx + 1) * 3 + (ky + 1)) * 3 + (kz + 1)) * CIN) * NF;
#pragma unroll
        for (int ci = 0; ci < CIN; ++ci) {
          const float fvv = fv[ci];
#pragma unroll
          for (int f = 0; f < NF; ++f) acc[f] = fmaf(fvv, wr[ci * NF + f], acc[f]);
        }
      }
    }
  }
  float4* op = reinterpret_cast<float4*>(out + (long long)v * NF);
  if (active) {
    op[0] = make_float4(acc[0], acc[1], acc[2], acc[3]);
    op[1] = make_float4(acc[4], acc[5], acc[6], acc[7]);
    op[2] = make_float4(acc[8], acc[9], acc[10], acc[11]);
    op[3] = make_float4(acc[12], acc[13], acc[14], acc[15]);
  } else {
    const float4 z4 = make_float4(0.f, 0.f, 0.f, 0.f);
    op[0] = z4; op[1] = z4; op[2] = z4; op[3] = z4;
  }
}

extern "C" void kernel_launch(void* const* d_in, const int* in_sizes, int n_in,
                              void* d_out, int out_size, void* d_ws, size_t ws_size,
                              hipStream_t stream) {
  const float* feat  = (const float*)d_in[0];
  const int*   index = (const int*)d_in[1];
  const float* w     = (const float*)d_in[2];
  const float* bias  = (const float*)d_in[3];
  float*       out   = (float*)d_out;

  const int nvox = in_sizes[1];  // 4*96*96*96

  if (ws_size < 14 * 64 * 8 * sizeof(short)) {
    sparse_conv_f32<<<nvox / 256, 256, 0, stream>>>(feat, index, w, bias, out);
    return;
  }

  short* wpack = (short*)d_ws;
  pack_w<<<1, 14 * 64, 0, stream>>>(w, wpack);

  const int blocks = 4 * 12 * 32;  // 1536 = 6 * 256 CUs — zero tail
  conv_mfma_pipe2<<<blocks, 512, 0, stream>>>(feat, index, bias,
                                              (const short8*)wpack, out);
}